// Round 2
// baseline (1315.243 us; speedup 1.0000x reference)
//
#include <hip/hip_runtime.h>
#include <stdint.h>

#define NNODES 50000
#define NEDGES 800000
#define KDIM 768
#define HID 512
#define NCLS 64

__device__ __forceinline__ float bf2f(unsigned short u){
  union { unsigned int i; float f; } c; c.i = ((unsigned int)u) << 16; return c.f;
}
__device__ __forceinline__ unsigned short f2bf(float f){
  union { float f; unsigned int i; } c; c.f = f;
  unsigned int r = c.i + 0x7FFFu + ((c.i >> 16) & 1u);  // RNE
  return (unsigned short)(r >> 16);
}

// Detect whether edge_index arrived as int64 (reference dtype) or int32
// (harness contract). int32 data misread as int64 has a nonzero high word
// with prob ~1 per sample; genuine int64 node indices are all < 2^31.
__global__ void detect_kernel(const void* __restrict__ p, int* __restrict__ flag){
  const unsigned long long* q = (const unsigned long long*)p;
  __shared__ int s;
  if (threadIdx.x == 0) s = 0;
  __syncthreads();
  unsigned long long v = q[threadIdx.x];
  if (v >> 31) atomicOr(&s, 1);
  __syncthreads();
  if (threadIdx.x == 0) *flag = (s ? 0 : 1);   // 1 => genuine int64
}

__global__ void convert_kernel(const void* __restrict__ p, int* __restrict__ srcI,
                               int* __restrict__ dstI, const int* __restrict__ flag){
  int i = blockIdx.x * blockDim.x + threadIdx.x;
  if (i >= NEDGES) return;
  if (*flag){
    const long long* q = (const long long*)p;
    srcI[i] = (int)q[i];
    dstI[i] = (int)q[NEDGES + i];
  } else {
    const int* q = (const int*)p;
    srcI[i] = q[i];
    dstI[i] = q[NEDGES + i];
  }
}

__global__ void count_kernel(const int* __restrict__ dstI, int* __restrict__ cnt){
  int i = blockIdx.x * blockDim.x + threadIdx.x;
  if (i < NEDGES) atomicAdd(&cnt[dstI[i]], 1);
}

// Single-block exclusive scan of per-node edge counts; also dis = rsqrt(deg+1).
__global__ void scan_kernel(const int* __restrict__ cnt, int* __restrict__ offs,
                            int* __restrict__ cursor, float* __restrict__ dis){
  __shared__ int sdata[256];
  int carry = 0;
  for (int base = 0; base < NNODES; base += 256){
    int i = base + threadIdx.x;
    int v = (i < NNODES) ? cnt[i] : 0;
    sdata[threadIdx.x] = v;
    __syncthreads();
    int x = v;
    for (int o = 1; o < 256; o <<= 1){
      int y = (threadIdx.x >= o) ? sdata[threadIdx.x - o] : 0;
      __syncthreads();
      x += y;
      sdata[threadIdx.x] = x;
      __syncthreads();
    }
    if (i < NNODES){
      int e = carry + x - v;     // exclusive prefix
      offs[i] = e;
      cursor[i] = e;
      dis[i] = rsqrtf((float)(v + 1));
    }
    int total = sdata[255];
    __syncthreads();
    carry += total;
  }
  if (threadIdx.x == 0) offs[NNODES] = carry;
}

__global__ void scatter_kernel(const int* __restrict__ srcI, const int* __restrict__ dstI,
                               int* __restrict__ cursor, int* __restrict__ ssrc){
  int i = blockIdx.x * blockDim.x + threadIdx.x;
  if (i < NEDGES){
    int d = dstI[i];
    int p = atomicAdd(&cursor[d], 1);
    ssrc[p] = srcI[i];
  }
}

// fp32 SGEMM, bf16 output. 256 threads, TMxTN microtile per thread.
template<int BM, int BN, int BK, int TM, int TN, bool RELU>
__global__ __launch_bounds__(256) void sgemm_bf16(
    const float* __restrict__ A, const float* __restrict__ B,
    unsigned short* __restrict__ C, int M, int N, int K){
  constexpr int TX = BN / TN;
  constexpr int TY = BM / TM;
  constexpr int NT = TX * TY;            // 256
  constexpr int KQ = BK / 4;
  constexpr int A4 = (BM * BK) / (4 * NT);
  constexpr int B4 = (BN * BK) / (4 * NT);
  __shared__ float As[BK][BM + 4];
  __shared__ float Bs[BK][BN + 4];
  const int t = threadIdx.x;
  const int tx = t % TX, ty = t / TX;
  const int row0 = blockIdx.y * BM;
  const int col0 = blockIdx.x * BN;
  float acc[TM][TN];
  #pragma unroll
  for (int j = 0; j < TM; j++)
    #pragma unroll
    for (int i = 0; i < TN; i++) acc[j][i] = 0.f;

  for (int k0 = 0; k0 < K; k0 += BK){
    #pragma unroll
    for (int i = 0; i < A4; i++){
      int f = i * NT + t;
      int r = f / KQ;
      int kq = f % KQ;
      int gr = row0 + r;
      float4 v = make_float4(0.f, 0.f, 0.f, 0.f);
      if (gr < M){
        v = *(const float4*)(A + (size_t)gr * K + k0 + kq * 4);
        if (RELU){
          v.x = fmaxf(v.x, 0.f); v.y = fmaxf(v.y, 0.f);
          v.z = fmaxf(v.z, 0.f); v.w = fmaxf(v.w, 0.f);
        }
      }
      As[kq * 4 + 0][r] = v.x; As[kq * 4 + 1][r] = v.y;
      As[kq * 4 + 2][r] = v.z; As[kq * 4 + 3][r] = v.w;
    }
    #pragma unroll
    for (int i = 0; i < B4; i++){
      int f = i * NT + t;
      int kk = f / (BN / 4);
      int cq = f % (BN / 4);
      float4 v = *(const float4*)(B + (size_t)(k0 + kk) * N + col0 + cq * 4);
      *(float4*)&Bs[kk][cq * 4] = v;
    }
    __syncthreads();
    #pragma unroll
    for (int kk = 0; kk < BK; kk++){
      float a[TM], b[TN];
      #pragma unroll
      for (int j = 0; j < TM; j++) a[j] = As[kk][ty * TM + j];
      #pragma unroll
      for (int i = 0; i < TN; i++) b[i] = Bs[kk][tx * TN + i];
      #pragma unroll
      for (int j = 0; j < TM; j++)
        #pragma unroll
        for (int i = 0; i < TN; i++) acc[j][i] += a[j] * b[i];
    }
    __syncthreads();
  }
  #pragma unroll
  for (int j = 0; j < TM; j++){
    int gr = row0 + ty * TM + j;
    if (gr < M){
      unsigned int* cp = (unsigned int*)(C + (size_t)gr * N + col0 + tx * TN);
      #pragma unroll
      for (int i = 0; i < TN / 2; i++){
        unsigned int lo = f2bf(acc[j][2 * i]);
        unsigned int hi = f2bf(acc[j][2 * i + 1]);
        cp[i] = lo | (hi << 16);
      }
    }
  }
}

// Layer-1 aggregation: one 128-thread block per dst node, 4 cols/thread.
__global__ __launch_bounds__(128) void agg1_kernel(
    const unsigned short* __restrict__ h1, const int* __restrict__ offs,
    const int* __restrict__ ssrc, const float* __restrict__ dis,
    const float* __restrict__ b1, float* __restrict__ out){
  int d = blockIdx.x;
  int c = threadIdx.x * 4;
  int beg = offs[d], end = offs[d + 1];
  float a0 = 0.f, a1 = 0.f, a2 = 0.f, a3 = 0.f;
  for (int i = beg; i < end; i++){
    int s = ssrc[i];
    float w = dis[s];
    ushort4 hv = *(const ushort4*)(h1 + (size_t)s * HID + c);
    a0 += w * bf2f(hv.x); a1 += w * bf2f(hv.y);
    a2 += w * bf2f(hv.z); a3 += w * bf2f(hv.w);
  }
  float wd = dis[d];
  ushort4 hd = *(const ushort4*)(h1 + (size_t)d * HID + c);
  a0 += wd * bf2f(hd.x); a1 += wd * bf2f(hd.y);
  a2 += wd * bf2f(hd.z); a3 += wd * bf2f(hd.w);
  float4 bv = *(const float4*)(b1 + c);
  float4 o;
  o.x = a0 * wd + bv.x; o.y = a1 * wd + bv.y;
  o.z = a2 * wd + bv.z; o.w = a3 * wd + bv.w;
  *(float4*)(out + (size_t)d * HID + c) = o;
}

// Layer-2 aggregation: one wave per dst node (4 nodes per 256-thread block).
__global__ __launch_bounds__(256) void agg2_kernel(
    const unsigned short* __restrict__ h2, const int* __restrict__ offs,
    const int* __restrict__ ssrc, const float* __restrict__ dis,
    const float* __restrict__ b2, float* __restrict__ out){
  int d = blockIdx.x * 4 + (threadIdx.x >> 6);
  if (d >= NNODES) return;
  int lane = threadIdx.x & 63;
  int beg = offs[d], end = offs[d + 1];
  float a = 0.f;
  for (int i = beg; i < end; i++){
    int s = ssrc[i];
    a += dis[s] * bf2f(h2[(size_t)s * NCLS + lane]);
  }
  float wd = dis[d];
  a += wd * bf2f(h2[(size_t)d * NCLS + lane]);
  out[(size_t)d * NCLS + lane] = a * wd + b2[lane];
}

extern "C" void kernel_launch(void* const* d_in, const int* in_sizes, int n_in,
                              void* d_out, int out_size, void* d_ws, size_t ws_size,
                              hipStream_t stream){
  const float* X  = (const float*)d_in[0];
  const void*  EI = d_in[1];
  const float* W1 = (const float*)d_in[2];
  const float* b1 = (const float*)d_in[3];
  const float* W2 = (const float*)d_in[4];
  const float* b2 = (const float*)d_in[5];
  float* out = (float*)d_out;

  char* ws = (char*)d_ws;
  size_t off = 0;
  auto alloc = [&](size_t bytes) -> char* {
    char* p = ws + off;
    off = (off + bytes + 255) & ~(size_t)255;
    return p;
  };
  float* dis    = (float*)alloc((size_t)NNODES * 4);
  int*   cnt    = (int*)  alloc((size_t)NNODES * 4);
  int*   offs   = (int*)  alloc((size_t)(NNODES + 1) * 4);
  int*   cursor = (int*)  alloc((size_t)NNODES * 4);
  int*   srcI   = (int*)  alloc((size_t)NEDGES * 4);
  int*   dstI   = (int*)  alloc((size_t)NEDGES * 4);
  int*   ssrc   = (int*)  alloc((size_t)NEDGES * 4);
  int*   flag   = (int*)  alloc(4);
  unsigned short* h1 = (unsigned short*)alloc((size_t)NNODES * HID * 2);
  unsigned short* h2 = (unsigned short*)alloc((size_t)NNODES * NCLS * 2);

  hipMemsetAsync(cnt, 0, (size_t)NNODES * 4, stream);
  detect_kernel<<<1, 256, 0, stream>>>(EI, flag);
  convert_kernel<<<(NEDGES + 255) / 256, 256, 0, stream>>>(EI, srcI, dstI, flag);
  count_kernel<<<(NEDGES + 255) / 256, 256, 0, stream>>>(dstI, cnt);
  scan_kernel<<<1, 256, 0, stream>>>(cnt, offs, cursor, dis);
  scatter_kernel<<<(NEDGES + 255) / 256, 256, 0, stream>>>(srcI, dstI, cursor, ssrc);

  // h1 = X @ W1  (M=NNODES, N=HID, K=KDIM), bf16 out
  sgemm_bf16<128, 128, 16, 8, 8, false>
      <<<dim3(HID / 128, (NNODES + 127) / 128), 256, 0, stream>>>(X, W1, h1, NNODES, HID, KDIM);

  // x1 = aggregate(h1) + b1  -> d_out (fp32)
  agg1_kernel<<<NNODES, 128, 0, stream>>>(h1, offs, ssrc, dis, b1, out);

  // h2 = relu(x1) @ W2  (M=NNODES, N=NCLS, K=HID), relu applied on A-load
  sgemm_bf16<64, 64, 16, 4, 4, true>
      <<<dim3(NCLS / 64, (NNODES + 63) / 64), 256, 0, stream>>>(out, W2, h2, NNODES, NCLS, HID);

  // logits = aggregate(h2) + b2 -> d_out tail
  agg2_kernel<<<(NNODES + 3) / 4, 256, 0, stream>>>(h2, offs, ssrc, dis, b2,
                                                    out + (size_t)NNODES * HID);
}

// Round 5
// 803.514 us; speedup vs baseline: 1.6369x; 1.6369x over previous
//
#include <hip/hip_runtime.h>
#include <hip/hip_bf16.h>
#include <stdint.h>

#define NNODES 50000
#define NEDGES 800000
#define KDIM 768
#define HID 512
#define NCLS 64

typedef __attribute__((ext_vector_type(8))) short bf16x8;
typedef __attribute__((ext_vector_type(4))) float f32x4;

__device__ __forceinline__ float bf2f(unsigned short u){
  union { unsigned int i; float f; } c; c.i = ((unsigned int)u) << 16; return c.f;
}
__device__ __forceinline__ unsigned short f2bf(float f){
  union { float f; unsigned int i; } c; c.f = f;
  unsigned int r = c.i + 0x7FFFu + ((c.i >> 16) & 1u);  // RNE
  return (unsigned short)(r >> 16);
}
// Compiler-native conversion -> v_cvt_pk_bf16_f32 pairs (do NOT hand-roll; m240)
__device__ __forceinline__ short bfbits(float x){
  __hip_bfloat16 h = __float2bfloat16(x);
  return __builtin_bit_cast(short, h);
}

// ---------------- edge preprocessing (unchanged, validated round 2) ----------

__global__ void detect_kernel(const void* __restrict__ p, int* __restrict__ flag){
  const unsigned long long* q = (const unsigned long long*)p;
  __shared__ int s;
  if (threadIdx.x == 0) s = 0;
  __syncthreads();
  unsigned long long v = q[threadIdx.x];
  if (v >> 31) atomicOr(&s, 1);
  __syncthreads();
  if (threadIdx.x == 0) *flag = (s ? 0 : 1);   // 1 => genuine int64
}

__global__ void convert_kernel(const void* __restrict__ p, int* __restrict__ srcI,
                               int* __restrict__ dstI, const int* __restrict__ flag){
  int i = blockIdx.x * blockDim.x + threadIdx.x;
  if (i >= NEDGES) return;
  if (*flag){
    const long long* q = (const long long*)p;
    srcI[i] = (int)q[i];
    dstI[i] = (int)q[NEDGES + i];
  } else {
    const int* q = (const int*)p;
    srcI[i] = q[i];
    dstI[i] = q[NEDGES + i];
  }
}

__global__ void count_kernel(const int* __restrict__ dstI, int* __restrict__ cnt){
  int i = blockIdx.x * blockDim.x + threadIdx.x;
  if (i < NEDGES) atomicAdd(&cnt[dstI[i]], 1);
}

__global__ void scan_kernel(const int* __restrict__ cnt, int* __restrict__ offs,
                            int* __restrict__ cursor, float* __restrict__ dis){
  __shared__ int sdata[256];
  int carry = 0;
  for (int base = 0; base < NNODES; base += 256){
    int i = base + threadIdx.x;
    int v = (i < NNODES) ? cnt[i] : 0;
    sdata[threadIdx.x] = v;
    __syncthreads();
    int x = v;
    for (int o = 1; o < 256; o <<= 1){
      int y = (threadIdx.x >= o) ? sdata[threadIdx.x - o] : 0;
      __syncthreads();
      x += y;
      sdata[threadIdx.x] = x;
      __syncthreads();
    }
    if (i < NNODES){
      int e = carry + x - v;
      offs[i] = e;
      cursor[i] = e;
      dis[i] = rsqrtf((float)(v + 1));
    }
    int total = sdata[255];
    __syncthreads();
    carry += total;
  }
  if (threadIdx.x == 0) offs[NNODES] = carry;
}

__global__ void scatter_kernel(const int* __restrict__ srcI, const int* __restrict__ dstI,
                               int* __restrict__ cursor, int* __restrict__ ssrc){
  int i = blockIdx.x * blockDim.x + threadIdx.x;
  if (i < NEDGES){
    int d = dstI[i];
    int p = atomicAdd(&cursor[d], 1);
    ssrc[p] = srcI[i];
  }
}

// ------------- weight transpose + bf16 + chunk-swizzle -----------------------
// BT[n][k] layout, with 16B k-chunks pre-permuted by (chunk ^ (n&7)) within
// each 64-elem K-tile so global_load_lds can copy LINEARLY and the MFMA
// ds_read applies the same XOR (rule #21: same involution on both sides).
__global__ void wtrans_kernel(const float* __restrict__ W, unsigned short* __restrict__ BT,
                              int K, int N){
  int idx = blockIdx.x * 256 + threadIdx.x;
  if (idx >= K * N) return;
  int n = idx / K, k = idx - n * K;
  int c = (k >> 3) & 7;
  int sw = (k & ~63) | ((c ^ (n & 7)) << 3) | (k & 7);
  BT[(size_t)n * K + sw] = f2bf(W[(size_t)k * N + n]);
}

// ------------- MFMA GEMM: C[M,N] bf16 = A[M,K] fp32 (reg-staged->bf16) x B ---
// BT is bf16 [N,K] pre-swizzled. 256 threads = 4 waves (2x2), BK=64.
// Wave tile = (BM/2)x(BN/2); FM=BM/32, FN=BN/32 frags of 16x16.
template<int BM, int BN, bool RELU>
__global__ __launch_bounds__(256) void mfma_gemm(
    const float* __restrict__ A, const unsigned short* __restrict__ BTs,
    unsigned short* __restrict__ C, int M, int N, int K){
  constexpr int FM = BM / 32;
  constexpr int FN = BN / 32;
  constexpr int ACH = BM / 32;     // A 16B-chunks per thread per K-step
  constexpr int BCH = BN / 32;     // B 16B-chunks per thread per K-step
  __shared__ unsigned short lds[(BM + BN) * 64];
  unsigned short* As = lds;
  unsigned short* Bs = lds + BM * 64;

  const int tid = threadIdx.x;
  const int w = tid >> 6, lane = tid & 63;
  const int lr = lane & 15, lk = lane >> 4;
  const int row0 = blockIdx.y * BM, col0 = blockIdx.x * BN;
  const int wm = (w >> 1) * (BM / 2), wn = (w & 1) * (BN / 2);

  f32x4 acc[FM][FN];
  #pragma unroll
  for (int m = 0; m < FM; m++)
    #pragma unroll
    for (int n = 0; n < FN; n++)
      acc[m][n] = (f32x4){0.f, 0.f, 0.f, 0.f};

  const int nkt = K >> 6;
  for (int kt = 0; kt < nkt; ++kt){
    // --- stage B: linear global_load_lds (source pre-swizzled) ---
    #pragma unroll
    for (int t = 0; t < BCH; t++){
      int cib = (w * BCH + t) * 64;            // wave-uniform chunk base
      int ci = cib + lane;
      int r = ci >> 3, c = ci & 7;
      const unsigned short* src = BTs + (size_t)(col0 + r) * K + kt * 64 + c * 8;
      __builtin_amdgcn_global_load_lds(
          (const __attribute__((address_space(1))) unsigned int*)src,
          (__attribute__((address_space(3))) unsigned int*)(Bs + cib * 8), 16, 0, 0);
    }
    // --- stage A: reg-staged fp32 load -> bf16 -> swizzled ds_write_b128 ---
    #pragma unroll
    for (int t = 0; t < ACH; t++){
      int ci = t * 256 + tid;
      int r = ci >> 3, c = ci & 7;
      int gr = row0 + r; if (gr > M - 1) gr = M - 1;   // tail clamp (no OOB)
      const float* src = A + (size_t)gr * K + kt * 64 + c * 8;
      float4 v0 = *(const float4*)src;
      float4 v1 = *(const float4*)(src + 4);
      if (RELU){
        v0.x = fmaxf(v0.x, 0.f); v0.y = fmaxf(v0.y, 0.f);
        v0.z = fmaxf(v0.z, 0.f); v0.w = fmaxf(v0.w, 0.f);
        v1.x = fmaxf(v1.x, 0.f); v1.y = fmaxf(v1.y, 0.f);
        v1.z = fmaxf(v1.z, 0.f); v1.w = fmaxf(v1.w, 0.f);
      }
      bf16x8 pk;
      pk[0] = bfbits(v0.x); pk[1] = bfbits(v0.y);
      pk[2] = bfbits(v0.z); pk[3] = bfbits(v0.w);
      pk[4] = bfbits(v1.x); pk[5] = bfbits(v1.y);
      pk[6] = bfbits(v1.z); pk[7] = bfbits(v1.w);
      *(bf16x8*)(As + r * 64 + ((c ^ (r & 7)) << 3)) = pk;
    }
    __syncthreads();   // drains vmcnt (global_load_lds) + lgkmcnt (ds_write)

    #pragma unroll
    for (int ksl = 0; ksl < 2; ksl++){
      bf16x8 af[FM], bfr[FN];
      #pragma unroll
      for (int m = 0; m < FM; m++){
        int rowA = wm + m * 16 + lr;
        int ch = (lk + ksl * 4) ^ (rowA & 7);
        af[m] = *(const bf16x8*)(As + rowA * 64 + ch * 8);
      }
      #pragma unroll
      for (int n = 0; n < FN; n++){
        int colB = wn + n * 16 + lr;
        int ch = (lk + ksl * 4) ^ (colB & 7);
        bfr[n] = *(const bf16x8*)(Bs + colB * 64 + ch * 8);
      }
      #pragma unroll
      for (int m = 0; m < FM; m++)
        #pragma unroll
        for (int n = 0; n < FN; n++)
          acc[m][n] = __builtin_amdgcn_mfma_f32_16x16x32_bf16(af[m], bfr[n], acc[m][n], 0, 0, 0);
    }
    __syncthreads();
  }

  // epilogue: C/D layout col=lane&15, row=(lane>>4)*4+reg (m89/m91)
  #pragma unroll
  for (int m = 0; m < FM; m++){
    int rowb = row0 + wm + m * 16 + lk * 4;
    #pragma unroll
    for (int q = 0; q < 4; q++){
      if (rowb + q < M){
        #pragma unroll
        for (int n = 0; n < FN; n++){
          int col = col0 + wn + n * 16 + lr;
          C[(size_t)(rowb + q) * N + col] = f2bf(acc[m][n][q]);
        }
      }
    }
  }
}

// ------------- aggregations (unchanged, validated round 2) -------------------

__global__ __launch_bounds__(128) void agg1_kernel(
    const unsigned short* __restrict__ h1, const int* __restrict__ offs,
    const int* __restrict__ ssrc, const float* __restrict__ dis,
    const float* __restrict__ b1, float* __restrict__ out){
  int d = blockIdx.x;
  int c = threadIdx.x * 4;
  int beg = offs[d], end = offs[d + 1];
  float a0 = 0.f, a1 = 0.f, a2 = 0.f, a3 = 0.f;
  for (int i = beg; i < end; i++){
    int s = ssrc[i];
    float w = dis[s];
    ushort4 hv = *(const ushort4*)(h1 + (size_t)s * HID + c);
    a0 += w * bf2f(hv.x); a1 += w * bf2f(hv.y);
    a2 += w * bf2f(hv.z); a3 += w * bf2f(hv.w);
  }
  float wd = dis[d];
  ushort4 hd = *(const ushort4*)(h1 + (size_t)d * HID + c);
  a0 += wd * bf2f(hd.x); a1 += wd * bf2f(hd.y);
  a2 += wd * bf2f(hd.z); a3 += wd * bf2f(hd.w);
  float4 bv = *(const float4*)(b1 + c);
  float4 o;
  o.x = a0 * wd + bv.x; o.y = a1 * wd + bv.y;
  o.z = a2 * wd + bv.z; o.w = a3 * wd + bv.w;
  *(float4*)(out + (size_t)d * HID + c) = o;
}

__global__ __launch_bounds__(256) void agg2_kernel(
    const unsigned short* __restrict__ h2, const int* __restrict__ offs,
    const int* __restrict__ ssrc, const float* __restrict__ dis,
    const float* __restrict__ b2, float* __restrict__ out){
  int d = blockIdx.x * 4 + (threadIdx.x >> 6);
  if (d >= NNODES) return;
  int lane = threadIdx.x & 63;
  int beg = offs[d], end = offs[d + 1];
  float a = 0.f;
  for (int i = beg; i < end; i++){
    int s = ssrc[i];
    a += dis[s] * bf2f(h2[(size_t)s * NCLS + lane]);
  }
  float wd = dis[d];
  a += wd * bf2f(h2[(size_t)d * NCLS + lane]);
  out[(size_t)d * NCLS + lane] = a * wd + b2[lane];
}

// ---------------------------------------------------------------------------

extern "C" void kernel_launch(void* const* d_in, const int* in_sizes, int n_in,
                              void* d_out, int out_size, void* d_ws, size_t ws_size,
                              hipStream_t stream){
  const float* X  = (const float*)d_in[0];
  const void*  EI = d_in[1];
  const float* W1 = (const float*)d_in[2];
  const float* b1 = (const float*)d_in[3];
  const float* W2 = (const float*)d_in[4];
  const float* b2 = (const float*)d_in[5];
  float* out = (float*)d_out;

  char* ws = (char*)d_ws;
  size_t off = 0;
  auto alloc = [&](size_t bytes) -> char* {
    char* p = ws + off;
    off = (off + bytes + 255) & ~(size_t)255;
    return p;
  };
  float* dis    = (float*)alloc((size_t)NNODES * 4);
  int*   cnt    = (int*)  alloc((size_t)NNODES * 4);
  int*   offs   = (int*)  alloc((size_t)(NNODES + 1) * 4);
  int*   cursor = (int*)  alloc((size_t)NNODES * 4);
  int*   srcI   = (int*)  alloc((size_t)NEDGES * 4);
  int*   dstI   = (int*)  alloc((size_t)NEDGES * 4);
  int*   ssrc   = (int*)  alloc((size_t)NEDGES * 4);
  int*   flag   = (int*)  alloc(4);
  unsigned short* h1  = (unsigned short*)alloc((size_t)NNODES * HID * 2);
  unsigned short* h2  = (unsigned short*)alloc((size_t)NNODES * NCLS * 2);
  unsigned short* BT1 = (unsigned short*)alloc((size_t)HID * KDIM * 2);
  unsigned short* BT2 = (unsigned short*)alloc((size_t)NCLS * HID * 2);

  hipMemsetAsync(cnt, 0, (size_t)NNODES * 4, stream);
  detect_kernel<<<1, 256, 0, stream>>>(EI, flag);
  convert_kernel<<<(NEDGES + 255) / 256, 256, 0, stream>>>(EI, srcI, dstI, flag);
  count_kernel<<<(NEDGES + 255) / 256, 256, 0, stream>>>(dstI, cnt);
  scan_kernel<<<1, 256, 0, stream>>>(cnt, offs, cursor, dis);
  scatter_kernel<<<(NEDGES + 255) / 256, 256, 0, stream>>>(srcI, dstI, cursor, ssrc);

  wtrans_kernel<<<(KDIM * HID + 255) / 256, 256, 0, stream>>>(W1, BT1, KDIM, HID);
  wtrans_kernel<<<(HID * NCLS + 255) / 256, 256, 0, stream>>>(W2, BT2, HID, NCLS);

  // h1 = bf16(X) @ bf16(W1)   (M=50000, N=512, K=768)
  mfma_gemm<128, 128, false>
      <<<dim3(HID / 128, (NNODES + 127) / 128), 256, 0, stream>>>(X, BT1, h1, NNODES, HID, KDIM);

  // x1 = aggregate(h1) + b1 -> d_out (fp32)
  agg1_kernel<<<NNODES, 128, 0, stream>>>(h1, offs, ssrc, dis, b1, out);

  // h2 = bf16(relu(x1)) @ bf16(W2)  (M=50000, N=64, K=512), relu fused in A-staging
  mfma_gemm<64, 64, true>
      <<<dim3(NCLS / 64, (NNODES + 63) / 64), 256, 0, stream>>>(out, BT2, h2, NNODES, NCLS, HID);

  // logits = aggregate(h2) + b2 -> d_out tail
  agg2_kernel<<<(NNODES + 3) / 4, 256, 0, stream>>>(h2, offs, ssrc, dis, b2,
                                                    out + (size_t)NNODES * HID);
}

// Round 7
// 620.365 us; speedup vs baseline: 2.1201x; 1.2952x over previous
//
#include <hip/hip_runtime.h>
#include <hip/hip_bf16.h>
#include <stdint.h>

#define NNODES 50000
#define NEDGES 800000
#define KDIM 768
#define HID 512
#define NCLS 64
#define SCAN_BLOCKS ((NNODES + 255) / 256)   // 196

typedef __attribute__((ext_vector_type(8))) short bf16x8;
typedef __attribute__((ext_vector_type(4))) float f32x4;

__device__ __forceinline__ float bf2f(unsigned short u){
  union { unsigned int i; float f; } c; c.i = ((unsigned int)u) << 16; return c.f;
}
__device__ __forceinline__ unsigned short f2bf(float f){
  union { float f; unsigned int i; } c; c.f = f;
  unsigned int r = c.i + 0x7FFFu + ((c.i >> 16) & 1u);  // RNE
  return (unsigned short)(r >> 16);
}
// Compiler-native conversion -> v_cvt_pk_bf16_f32 pairs (do NOT hand-roll; m240)
__device__ __forceinline__ short bfbits(float x){
  __hip_bfloat16 h = __float2bfloat16(x);
  return __builtin_bit_cast(short, h);
}

// ---------------- edge preprocessing ----------------------------------------

__global__ void detect_kernel(const void* __restrict__ p, int* __restrict__ flag){
  const unsigned long long* q = (const unsigned long long*)p;
  __shared__ int s;
  if (threadIdx.x == 0) s = 0;
  __syncthreads();
  unsigned long long v = q[threadIdx.x];
  if (v >> 31) atomicOr(&s, 1);
  __syncthreads();
  if (threadIdx.x == 0) *flag = (s ? 0 : 1);   // 1 => genuine int64
}

__global__ void convert_kernel(const void* __restrict__ p, int* __restrict__ srcI,
                               int* __restrict__ dstI, const int* __restrict__ flag){
  int i = blockIdx.x * blockDim.x + threadIdx.x;
  if (i >= NEDGES) return;
  if (*flag){
    const long long* q = (const long long*)p;
    srcI[i] = (int)q[i];
    dstI[i] = (int)q[NEDGES + i];
  } else {
    const int* q = (const int*)p;
    srcI[i] = q[i];
    dstI[i] = q[NEDGES + i];
  }
}

__global__ void count_kernel(const int* __restrict__ dstI, int* __restrict__ cnt){
  int i = blockIdx.x * blockDim.x + threadIdx.x;
  if (i < NEDGES) atomicAdd(&cnt[dstI[i]], 1);
}

// --- two-level parallel scan (replaces 186us single-block scan; round-5 PMC:
//     0.046% occupancy, 0.02% VALUBusy -> pure serial latency) ---------------

__global__ __launch_bounds__(256) void scan1_kernel(const int* __restrict__ cnt,
                                                    int* __restrict__ offs,
                                                    int* __restrict__ bsum){
  __shared__ int sdata[256];
  int i = blockIdx.x * 256 + threadIdx.x;
  int v = (i < NNODES) ? cnt[i] : 0;
  sdata[threadIdx.x] = v;
  __syncthreads();
  int x = v;
  for (int o = 1; o < 256; o <<= 1){
    int y = (threadIdx.x >= o) ? sdata[threadIdx.x - o] : 0;
    __syncthreads();
    x += y;
    sdata[threadIdx.x] = x;
    __syncthreads();
  }
  if (i < NNODES) offs[i] = x - v;            // local exclusive prefix
  if (threadIdx.x == 255) bsum[blockIdx.x] = x;  // block total
}

__global__ __launch_bounds__(256) void scan2_kernel(int* __restrict__ bsum){
  __shared__ int sdata[256];
  int v = (threadIdx.x < SCAN_BLOCKS) ? bsum[threadIdx.x] : 0;
  sdata[threadIdx.x] = v;
  __syncthreads();
  int x = v;
  for (int o = 1; o < 256; o <<= 1){
    int y = (threadIdx.x >= o) ? sdata[threadIdx.x - o] : 0;
    __syncthreads();
    x += y;
    sdata[threadIdx.x] = x;
    __syncthreads();
  }
  if (threadIdx.x < SCAN_BLOCKS) bsum[threadIdx.x] = x - v;  // exclusive
}

__global__ __launch_bounds__(256) void scan3_kernel(const int* __restrict__ cnt,
                                                    int* __restrict__ offs,
                                                    const int* __restrict__ bsum,
                                                    int* __restrict__ cursor,
                                                    float* __restrict__ dis){
  int i = blockIdx.x * 256 + threadIdx.x;
  if (i < NNODES){
    int e = offs[i] + bsum[blockIdx.x];
    offs[i] = e;
    cursor[i] = e;
    dis[i] = rsqrtf((float)(cnt[i] + 1));
  }
  if (i == 0) offs[NNODES] = NEDGES;   // total is statically known
}

__global__ void scatter_kernel(const int* __restrict__ srcI, const int* __restrict__ dstI,
                               int* __restrict__ cursor, int* __restrict__ ssrc){
  int i = blockIdx.x * blockDim.x + threadIdx.x;
  if (i < NEDGES){
    int d = dstI[i];
    int p = atomicAdd(&cursor[d], 1);
    ssrc[p] = srcI[i];
  }
}

// ------------- weight transpose + bf16 + chunk-swizzle -----------------------
// BT[n][k] layout, with 16B k-chunks pre-permuted by (chunk ^ (n&7)) within
// each 64-elem K-tile so global_load_lds can copy LINEARLY and the MFMA
// ds_read applies the same XOR (rule #21: same involution on both sides).
__global__ void wtrans_kernel(const float* __restrict__ W, unsigned short* __restrict__ BT,
                              int K, int N){
  int idx = blockIdx.x * 256 + threadIdx.x;
  if (idx >= K * N) return;
  int n = idx / K, k = idx - n * K;
  int c = (k >> 3) & 7;
  int sw = (k & ~63) | ((c ^ (n & 7)) << 3) | (k & 7);
  BT[(size_t)n * K + sw] = f2bf(W[(size_t)k * N + n]);
}

// ------------- MFMA GEMM: C[M,N] bf16 = A[M,K] fp32 (reg-staged->bf16) x B ---
// BT is bf16 [N,K] pre-swizzled. 256 threads = 4 waves (2x2), BK=64.
// Wave tile = (BM/2)x(BN/2); FM=BM/32, FN=BN/32 frags of 16x16.
template<int BM, int BN, bool RELU>
__global__ __launch_bounds__(256) void mfma_gemm(
    const float* __restrict__ A, const unsigned short* __restrict__ BTs,
    unsigned short* __restrict__ C, int M, int N, int K){
  constexpr int FM = BM / 32;
  constexpr int FN = BN / 32;
  constexpr int ACH = BM / 32;     // A 16B-chunks per thread per K-step
  constexpr int BCH = BN / 32;     // B 16B-chunks per thread per K-step
  __shared__ unsigned short lds[(BM + BN) * 64];
  unsigned short* As = lds;
  unsigned short* Bs = lds + BM * 64;

  const int tid = threadIdx.x;
  const int w = tid >> 6, lane = tid & 63;
  const int lr = lane & 15, lk = lane >> 4;
  const int row0 = blockIdx.y * BM, col0 = blockIdx.x * BN;
  const int wm = (w >> 1) * (BM / 2), wn = (w & 1) * (BN / 2);

  f32x4 acc[FM][FN];
  #pragma unroll
  for (int m = 0; m < FM; m++)
    #pragma unroll
    for (int n = 0; n < FN; n++)
      acc[m][n] = (f32x4){0.f, 0.f, 0.f, 0.f};

  const int nkt = K >> 6;
  for (int kt = 0; kt < nkt; ++kt){
    // --- stage B: linear global_load_lds (source pre-swizzled) ---
    #pragma unroll
    for (int t = 0; t < BCH; t++){
      int cib = (w * BCH + t) * 64;            // wave-uniform chunk base
      int ci = cib + lane;
      int r = ci >> 3, c = ci & 7;
      const unsigned short* src = BTs + (size_t)(col0 + r) * K + kt * 64 + c * 8;
      __builtin_amdgcn_global_load_lds(
          (const __attribute__((address_space(1))) unsigned int*)src,
          (__attribute__((address_space(3))) unsigned int*)(Bs + cib * 8), 16, 0, 0);
    }
    // --- stage A: reg-staged fp32 load -> bf16 -> swizzled ds_write_b128 ---
    #pragma unroll
    for (int t = 0; t < ACH; t++){
      int ci = t * 256 + tid;
      int r = ci >> 3, c = ci & 7;
      int gr = row0 + r; if (gr > M - 1) gr = M - 1;   // tail clamp (no OOB)
      const float* src = A + (size_t)gr * K + kt * 64 + c * 8;
      float4 v0 = *(const float4*)src;
      float4 v1 = *(const float4*)(src + 4);
      if (RELU){
        v0.x = fmaxf(v0.x, 0.f); v0.y = fmaxf(v0.y, 0.f);
        v0.z = fmaxf(v0.z, 0.f); v0.w = fmaxf(v0.w, 0.f);
        v1.x = fmaxf(v1.x, 0.f); v1.y = fmaxf(v1.y, 0.f);
        v1.z = fmaxf(v1.z, 0.f); v1.w = fmaxf(v1.w, 0.f);
      }
      bf16x8 pk;
      pk[0] = bfbits(v0.x); pk[1] = bfbits(v0.y);
      pk[2] = bfbits(v0.z); pk[3] = bfbits(v0.w);
      pk[4] = bfbits(v1.x); pk[5] = bfbits(v1.y);
      pk[6] = bfbits(v1.z); pk[7] = bfbits(v1.w);
      *(bf16x8*)(As + r * 64 + ((c ^ (r & 7)) << 3)) = pk;
    }
    __syncthreads();   // drains vmcnt (global_load_lds) + lgkmcnt (ds_write)

    #pragma unroll
    for (int ksl = 0; ksl < 2; ksl++){
      bf16x8 af[FM], bfr[FN];
      #pragma unroll
      for (int m = 0; m < FM; m++){
        int rowA = wm + m * 16 + lr;
        int ch = (lk + ksl * 4) ^ (rowA & 7);
        af[m] = *(const bf16x8*)(As + rowA * 64 + ch * 8);
      }
      #pragma unroll
      for (int n = 0; n < FN; n++){
        int colB = wn + n * 16 + lr;
        int ch = (lk + ksl * 4) ^ (colB & 7);
        bfr[n] = *(const bf16x8*)(Bs + colB * 64 + ch * 8);
      }
      #pragma unroll
      for (int m = 0; m < FM; m++)
        #pragma unroll
        for (int n = 0; n < FN; n++)
          acc[m][n] = __builtin_amdgcn_mfma_f32_16x16x32_bf16(af[m], bfr[n], acc[m][n], 0, 0, 0);
    }
    __syncthreads();
  }

  // epilogue: C/D layout col=lane&15, row=(lane>>4)*4+reg (m89/m91)
  #pragma unroll
  for (int m = 0; m < FM; m++){
    int rowb = row0 + wm + m * 16 + lk * 4;
    #pragma unroll
    for (int q = 0; q < 4; q++){
      if (rowb + q < M){
        #pragma unroll
        for (int n = 0; n < FN; n++){
          int col = col0 + wn + n * 16 + lr;
          C[(size_t)(rowb + q) * N + col] = f2bf(acc[m][n][q]);
        }
      }
    }
  }
}

// ------------- aggregations (unchanged, validated round 2/5) -----------------

__global__ __launch_bounds__(128) void agg1_kernel(
    const unsigned short* __restrict__ h1, const int* __restrict__ offs,
    const int* __restrict__ ssrc, const float* __restrict__ dis,
    const float* __restrict__ b1, float* __restrict__ out){
  int d = blockIdx.x;
  int c = threadIdx.x * 4;
  int beg = offs[d], end = offs[d + 1];
  float a0 = 0.f, a1 = 0.f, a2 = 0.f, a3 = 0.f;
  for (int i = beg; i < end; i++){
    int s = ssrc[i];
    float w = dis[s];
    ushort4 hv = *(const ushort4*)(h1 + (size_t)s * HID + c);
    a0 += w * bf2f(hv.x); a1 += w * bf2f(hv.y);
    a2 += w * bf2f(hv.z); a3 += w * bf2f(hv.w);
  }
  float wd = dis[d];
  ushort4 hd = *(const ushort4*)(h1 + (size_t)d * HID + c);
  a0 += wd * bf2f(hd.x); a1 += wd * bf2f(hd.y);
  a2 += wd * bf2f(hd.z); a3 += wd * bf2f(hd.w);
  float4 bv = *(const float4*)(b1 + c);
  float4 o;
  o.x = a0 * wd + bv.x; o.y = a1 * wd + bv.y;
  o.z = a2 * wd + bv.z; o.w = a3 * wd + bv.w;
  *(float4*)(out + (size_t)d * HID + c) = o;
}

__global__ __launch_bounds__(256) void agg2_kernel(
    const unsigned short* __restrict__ h2, const int* __restrict__ offs,
    const int* __restrict__ ssrc, const float* __restrict__ dis,
    const float* __restrict__ b2, float* __restrict__ out){
  int d = blockIdx.x * 4 + (threadIdx.x >> 6);
  if (d >= NNODES) return;
  int lane = threadIdx.x & 63;
  int beg = offs[d], end = offs[d + 1];
  float a = 0.f;
  for (int i = beg; i < end; i++){
    int s = ssrc[i];
    a += dis[s] * bf2f(h2[(size_t)s * NCLS + lane]);
  }
  float wd = dis[d];
  a += wd * bf2f(h2[(size_t)d * NCLS + lane]);
  out[(size_t)d * NCLS + lane] = a * wd + b2[lane];
}

// ---------------------------------------------------------------------------

extern "C" void kernel_launch(void* const* d_in, const int* in_sizes, int n_in,
                              void* d_out, int out_size, void* d_ws, size_t ws_size,
                              hipStream_t stream){
  const float* X  = (const float*)d_in[0];
  const void*  EI = d_in[1];
  const float* W1 = (const float*)d_in[2];
  const float* b1 = (const float*)d_in[3];
  const float* W2 = (const float*)d_in[4];
  const float* b2 = (const float*)d_in[5];
  float* out = (float*)d_out;

  char* ws = (char*)d_ws;
  size_t off = 0;
  auto alloc = [&](size_t bytes) -> char* {
    char* p = ws + off;
    off = (off + bytes + 255) & ~(size_t)255;
    return p;
  };
  float* dis    = (float*)alloc((size_t)NNODES * 4);
  int*   cnt    = (int*)  alloc((size_t)NNODES * 4);
  int*   offs   = (int*)  alloc((size_t)(NNODES + 1) * 4);
  int*   cursor = (int*)  alloc((size_t)NNODES * 4);
  int*   srcI   = (int*)  alloc((size_t)NEDGES * 4);
  int*   dstI   = (int*)  alloc((size_t)NEDGES * 4);
  int*   ssrc   = (int*)  alloc((size_t)NEDGES * 4);
  int*   flag   = (int*)  alloc(4);
  int*   bsum   = (int*)  alloc((size_t)SCAN_BLOCKS * 4);
  unsigned short* h1  = (unsigned short*)alloc((size_t)NNODES * HID * 2);
  unsigned short* h2  = (unsigned short*)alloc((size_t)NNODES * NCLS * 2);
  unsigned short* BT1 = (unsigned short*)alloc((size_t)HID * KDIM * 2);
  unsigned short* BT2 = (unsigned short*)alloc((size_t)NCLS * HID * 2);

  hipMemsetAsync(cnt, 0, (size_t)NNODES * 4, stream);
  detect_kernel<<<1, 256, 0, stream>>>(EI, flag);
  convert_kernel<<<(NEDGES + 255) / 256, 256, 0, stream>>>(EI, srcI, dstI, flag);
  count_kernel<<<(NEDGES + 255) / 256, 256, 0, stream>>>(dstI, cnt);
  scan1_kernel<<<SCAN_BLOCKS, 256, 0, stream>>>(cnt, offs, bsum);
  scan2_kernel<<<1, 256, 0, stream>>>(bsum);
  scan3_kernel<<<SCAN_BLOCKS, 256, 0, stream>>>(cnt, offs, bsum, cursor, dis);
  scatter_kernel<<<(NEDGES + 255) / 256, 256, 0, stream>>>(srcI, dstI, cursor, ssrc);

  wtrans_kernel<<<(KDIM * HID + 255) / 256, 256, 0, stream>>>(W1, BT1, KDIM, HID);
  wtrans_kernel<<<(HID * NCLS + 255) / 256, 256, 0, stream>>>(W2, BT2, HID, NCLS);

  // h1 = bf16(X) @ bf16(W1)   (M=50000, N=512, K=768)
  mfma_gemm<128, 128, false>
      <<<dim3(HID / 128, (NNODES + 127) / 128), 256, 0, stream>>>(X, BT1, h1, NNODES, HID, KDIM);

  // x1 = aggregate(h1) + b1 -> d_out (fp32)
  agg1_kernel<<<NNODES, 128, 0, stream>>>(h1, offs, ssrc, dis, b1, out);

  // h2 = bf16(relu(x1)) @ bf16(W2)  (M=50000, N=64, K=512), relu fused in A-staging
  mfma_gemm<64, 64, true>
      <<<dim3(NCLS / 64, (NNODES + 63) / 64), 256, 0, stream>>>(out, BT2, h2, NNODES, NCLS, HID);

  // logits = aggregate(h2) + b2 -> d_out tail
  agg2_kernel<<<(NNODES + 3) / 4, 256, 0, stream>>>(h2, offs, ssrc, dis, b2,
                                                    out + (size_t)NNODES * HID);
}